// Round 11
// baseline (27.000 us; speedup 1.0000x reference)
//
#include <hip/hip_runtime.h>
#include <hip/hip_bf16.h>

// Problem constants
#define NN 10
#define IN_DIM 65536
#define HEADS 8
#define DD 8
#define ROWS 320
#define MTILES 20
#define KGRPS 512             // one block per kgrp (k-slice of 128 floats)
#define KB_PER_GRP 4
#define KFLOATS 128
#define PAIRS (ROWS*HEADS)    // 2560
#define STAGES 5              // 4 mtiles (64 rows) per stage
#define LROW 136              // LDS row stride in bf16 elems (128 + 8 pad = 272 B)

typedef __attribute__((ext_vector_type(8))) short bf16x8;
typedef __attribute__((ext_vector_type(4))) float f32x4;
typedef unsigned short u16;

static __device__ __forceinline__ short f2bf(float f) {
    __hip_bfloat16 h = __float2bfloat16(f);
    return *reinterpret_cast<short*>(&h);
}

static __device__ __forceinline__ bf16x8 cvt8(float4 lo, float4 hi) {
    bf16x8 a;
    a[0]=f2bf(lo.x); a[1]=f2bf(lo.y); a[2]=f2bf(lo.z); a[3]=f2bf(lo.w);
    a[4]=f2bf(hi.x); a[5]=f2bf(hi.y); a[6]=f2bf(hi.z); a[7]=f2bf(hi.w);
    return a;
}

// 128-B-per-thread staging register set (kept in named regs; rule-#20 safe)
struct XR { float4 r0,r1,r2,r3,r4,r5,r6,r7; };

static __device__ __forceinline__ void load_stage(XR& d, const float* __restrict__ x,
                                                  int kgrp, int s, int t) {
    // thread t: global row 64*s + (t>>2), 32 contiguous floats at (t&3)*32.
    // 4 consecutive threads cover one row's full 512B slice contiguously.
    const float4* src = (const float4*)(x + (size_t)(64*s + (t>>2)) * IN_DIM
                                          + (size_t)kgrp * KFLOATS + (t&3)*32);
    d.r0=src[0]; d.r1=src[1]; d.r2=src[2]; d.r3=src[3];
    d.r4=src[4]; d.r5=src[5]; d.r6=src[6]; d.r7=src[7];
}

static __device__ __forceinline__ void write_stage(const XR& d, u16* dst) {
    bf16x8* p = (bf16x8*)dst;          // dst is 16B-aligned (row stride 272, col*64)
    p[0]=cvt8(d.r0,d.r1); p[1]=cvt8(d.r2,d.r3);
    p[2]=cvt8(d.r4,d.r5); p[3]=cvt8(d.r6,d.r7);
}

// ---------------------------------------------------------------------------
// Fused kernel: one block per kgrp (512 blocks = 2/CU).
// Phase 1: bake bf16 B-fragments (d-summed W) into LDS (R6-verified layout).
// Phase 2: LDS-staged x stream. Stage s covers mtiles 4s..4s+3 (64 rows x
// 128 floats = 32KB), loaded with fully-contiguous 512B runs (fixes the
// 16-rows-per-instruction address divergence of the direct-load version),
// bf16-converted, double-buffered in LDS; wave w computes mtile 4s+w via
// padded ds_read_b128 fragments. Loads for stage s+2 issue before compute s.
// ---------------------------------------------------------------------------
__global__ __launch_bounds__(256, 2) void gemv_fused_kernel(const float* __restrict__ x,
                                                            const float* __restrict__ W,
                                                            float* __restrict__ partials) {
    const int kgrp = blockIdx.x;
    const int t    = threadIdx.x;
    const int lane = t & 63;
    const int wave = t >> 6;       // 0..3

    __shared__ bf16x8 lds_b[KB_PER_GRP][64];                 // 4 KB
    __shared__ __align__(16) u16 xbuf[2][64][LROW];          // 34 KB

    XR A, B;
    // issue stage-0 global loads first (hide under the W bake)
    load_stage(A, x, kgrp, 0, t);

    // ---- phase 1: W -> B fragments in LDS ----
    {
        const int kbl  = t >> 6;         // kblock-local 0..3
        const int head = lane & 15;
        const int kq   = lane >> 4;      // 0..3
        bf16x8 o = {0,0,0,0,0,0,0,0};
        if (head < HEADS) {
            float s0=0,s1=0,s2=0,s3=0,s4=0,s5=0,s6=0,s7=0;
            const float* wbase = W + (size_t)(head * DD) * IN_DIM
                               + kgrp * KFLOATS + kbl * 32 + kq * 8;
#pragma unroll
            for (int d = 0; d < DD; ++d) {
                const float4* p = (const float4*)(wbase + (size_t)d * IN_DIM);
                float4 lo = p[0], hi = p[1];
                s0 += lo.x; s1 += lo.y; s2 += lo.z; s3 += lo.w;
                s4 += hi.x; s5 += hi.y; s6 += hi.z; s7 += hi.w;
            }
            o[0]=f2bf(s0); o[1]=f2bf(s1); o[2]=f2bf(s2); o[3]=f2bf(s3);
            o[4]=f2bf(s4); o[5]=f2bf(s5); o[6]=f2bf(s6); o[7]=f2bf(s7);
        }
        lds_b[kbl][lane] = o;
    }
    __syncthreads();                      // lds_b ready

    const bf16x8 b0 = lds_b[0][lane];
    const bf16x8 b1 = lds_b[1][lane];
    const bf16x8 b2 = lds_b[2][lane];
    const bf16x8 b3 = lds_b[3][lane];

    u16* wdst = &xbuf[0][0][0] + (size_t)(t >> 2) * LROW + (t & 3) * 32;  // buf0 slot
    const size_t bufstride = (size_t)64 * LROW;

    write_stage(A, wdst);                 // stage 0 -> buf0
    load_stage(B, x, kgrp, 1, t);         // stage 1 in flight
    __syncthreads();                      // buf0 ready

    const int head = lane & 15;
    const int r0   = (lane >> 4) * 4;
    const int kq   = lane >> 4;
    float* pbase = partials + (size_t)kgrp * PAIRS;
    // compute-side LDS row pointer for this wave (row = wave*16 + (lane&15))
    const u16* rowp = &xbuf[0][0][0] + (size_t)(wave * 16 + (lane & 15)) * LROW + kq * 8;

#define COMPUTE_STAGE(BUFIDX, MT)                                              \
    {                                                                          \
        const bf16x8* q = (const bf16x8*)(rowp + (BUFIDX) * bufstride);        \
        f32x4 acc = {0.f,0.f,0.f,0.f};                                         \
        acc = __builtin_amdgcn_mfma_f32_16x16x32_bf16(q[0],  b0, acc, 0,0,0);  \
        acc = __builtin_amdgcn_mfma_f32_16x16x32_bf16(q[4],  b1, acc, 0,0,0);  \
        acc = __builtin_amdgcn_mfma_f32_16x16x32_bf16(q[8],  b2, acc, 0,0,0);  \
        acc = __builtin_amdgcn_mfma_f32_16x16x32_bf16(q[12], b3, acc, 0,0,0);  \
        if (head < HEADS) {                                                    \
            _Pragma("unroll")                                                  \
            for (int j = 0; j < 4; ++j)                                        \
                pbase[(size_t)((MT)*16 + r0 + j) * HEADS + head] = acc[j];     \
        }                                                                      \
    }

    // ---- s=0: compute buf0 (stage 0), prefetch stage 2, write stage 1 ----
    load_stage(A, x, kgrp, 2, t);
    COMPUTE_STAGE(0, wave);
    __syncthreads();
    write_stage(B, wdst + bufstride);     // stage 1 -> buf1
    __syncthreads();

    // ---- s=1: compute buf1 (stage 1), prefetch stage 3, write stage 2 ----
    load_stage(B, x, kgrp, 3, t);
    COMPUTE_STAGE(1, 4 + wave);
    __syncthreads();
    write_stage(A, wdst);                 // stage 2 -> buf0
    __syncthreads();

    // ---- s=2: compute buf0 (stage 2), prefetch stage 4, write stage 3 ----
    load_stage(A, x, kgrp, 4, t);
    COMPUTE_STAGE(0, 8 + wave);
    __syncthreads();
    write_stage(B, wdst + bufstride);     // stage 3 -> buf1
    __syncthreads();

    // ---- s=3: compute buf1 (stage 3), write stage 4 ----
    COMPUTE_STAGE(1, 12 + wave);
    __syncthreads();
    write_stage(A, wdst);                 // stage 4 -> buf0
    __syncthreads();

    // ---- s=4: compute buf0 (stage 4) ----
    COMPUTE_STAGE(0, 16 + wave);
#undef COMPUTE_STAGE
}

// ---------------------------------------------------------------------------
// Finalize: tot[pair] = sum_g partials[g][pair];  pair = bn*8 + h
//           out[bn][h*10+m] = relu(tot * adj[bn][m])
// ---------------------------------------------------------------------------
__global__ __launch_bounds__(256) void finalize_kernel(const float* __restrict__ partials,
                                                       const float* __restrict__ adj,
                                                       float* __restrict__ out) {
    const int b  = blockIdx.x;       // 0..159
    const int t  = threadIdx.x;
    const int pr = t & 15;           // pair-in-block
    const int gs = t >> 4;           // 0..15 (each covers 32 kgrps)
    const int pair = b * 16 + pr;

    float s = 0.f;
    const float* p = partials + (size_t)gs * 32 * PAIRS + pair;
#pragma unroll 8
    for (int g = 0; g < 32; ++g)
        s += p[(size_t)g * PAIRS];

    __shared__ float red[16][16];
    red[gs][pr] = s;
    __syncthreads();

    if (t < 16) {
        float tot = 0.f;
#pragma unroll
        for (int i = 0; i < 16; ++i) tot += red[i][t];
        const int pair2 = b * 16 + t;
        const int bn = pair2 >> 3;
        const int h  = pair2 & 7;
        const float* a = adj + bn * NN;
        float* o = out + bn * (HEADS * NN) + h * NN;
#pragma unroll
        for (int m = 0; m < NN; ++m) {
            float v = tot * a[m];
            o[m] = v > 0.f ? v : 0.f;
        }
    }
}

extern "C" void kernel_launch(void* const* d_in, const int* in_sizes, int n_in,
                              void* d_out, int out_size, void* d_ws, size_t ws_size,
                              hipStream_t stream) {
    const float* x   = (const float*)d_in[0];   // (32,10,65536)
    const float* adj = (const float*)d_in[1];   // (32,10,10)
    const float* W   = (const float*)d_in[2];   // (64,65536)
    float* out = (float*)d_out;                 // (32,10,80)

    // workspace: partials (512 * 2560 f32 = 5.24 MB)
    float* partials = (float*)d_ws;

    // K1: fused W-bake + LDS-staged MFMA GEMV. 512 blocks (one per kgrp).
    gemv_fused_kernel<<<KGRPS, 256, 0, stream>>>(x, W, partials);

    // K2: finalize. 160 blocks.
    finalize_kernel<<<160, 256, 0, stream>>>(partials, adj, out);
}

// Round 12
// 24.803 us; speedup vs baseline: 1.0886x; 1.0886x over previous
//
#include <hip/hip_runtime.h>
#include <hip/hip_bf16.h>

// Problem constants
#define NN 10
#define IN_DIM 65536
#define HEADS 8
#define DD 8
#define ROWS 320
#define MTILES 20
#define KGRPS 512             // one block per kgrp (k-slice of 128 floats)
#define KB_PER_GRP 4
#define KFLOATS 128
#define PAIRS (ROWS*HEADS)    // 2560
#define LROW 136              // LDS row stride in u16 (128 + 8 pad = 272 B)

typedef __attribute__((ext_vector_type(8))) short bf16x8;
typedef __attribute__((ext_vector_type(4))) float f32x4;
typedef unsigned short u16;

static __device__ __forceinline__ short f2bf(float f) {
    __hip_bfloat16 h = __float2bfloat16(f);
    return *reinterpret_cast<short*>(&h);
}
static __device__ __forceinline__ u16 f2bfu(float f) {
    __hip_bfloat16 h = __float2bfloat16(f);
    return *reinterpret_cast<u16*>(&h);
}
static __device__ __forceinline__ ushort4 cvt4(float4 v) {
    ushort4 o; o.x=f2bfu(v.x); o.y=f2bfu(v.y); o.z=f2bfu(v.z); o.w=f2bfu(v.w);
    return o;
}

// 128-B-per-thread staging registers (named; rule-#20 safe)
struct XR { float4 r0,r1,r2,r3,r4,r5,r6,r7; };

// Instruction i covers rows 64s+i*8 .. +8 (2 rows/wave-instruction, each as a
// full contiguous 512B run): thread t -> row 64s + i*8 + (t>>5), bytes (t&31)*16.
static __device__ __forceinline__ void load_stage(XR& d, const float* __restrict__ x,
                                                  int kgrp, int s, int t) {
    const float* base = x + (size_t)kgrp * KFLOATS + (t & 31) * 4
                          + (size_t)(64 * s + (t >> 5)) * IN_DIM;
    d.r0 = *(const float4*)(base + (size_t)( 0) * IN_DIM);
    d.r1 = *(const float4*)(base + (size_t)( 8) * IN_DIM);
    d.r2 = *(const float4*)(base + (size_t)(16) * IN_DIM);
    d.r3 = *(const float4*)(base + (size_t)(24) * IN_DIM);
    d.r4 = *(const float4*)(base + (size_t)(32) * IN_DIM);
    d.r5 = *(const float4*)(base + (size_t)(40) * IN_DIM);
    d.r6 = *(const float4*)(base + (size_t)(48) * IN_DIM);
    d.r7 = *(const float4*)(base + (size_t)(56) * IN_DIM);
}

static __device__ __forceinline__ void write_stage(const XR& d, u16* __restrict__ buf, int t) {
    u16* p = buf + (size_t)(t >> 5) * LROW + (t & 31) * 4;
    *(ushort4*)(p + (size_t)( 0) * LROW) = cvt4(d.r0);
    *(ushort4*)(p + (size_t)( 8) * LROW) = cvt4(d.r1);
    *(ushort4*)(p + (size_t)(16) * LROW) = cvt4(d.r2);
    *(ushort4*)(p + (size_t)(24) * LROW) = cvt4(d.r3);
    *(ushort4*)(p + (size_t)(32) * LROW) = cvt4(d.r4);
    *(ushort4*)(p + (size_t)(40) * LROW) = cvt4(d.r5);
    *(ushort4*)(p + (size_t)(48) * LROW) = cvt4(d.r6);
    *(ushort4*)(p + (size_t)(56) * LROW) = cvt4(d.r7);
}

// ---------------------------------------------------------------------------
// Fused kernel: one block per kgrp (512 blocks = 2/CU).
// Phase 1: bake bf16 B-fragments (d-summed W) into LDS (R6-verified layout).
// Phase 2: LDS-staged x stream with PER-INSTRUCTION contiguity (2 rows x 512B
// per global load instruction — R11's version was only per-thread contiguous).
// Double-buffered stages of 64 rows; wave w computes mtile 4s+w from padded
// LDS; loads for stage s+2 issue before compute of stage s.
// ---------------------------------------------------------------------------
__global__ __launch_bounds__(256, 2) void gemv_fused_kernel(const float* __restrict__ x,
                                                            const float* __restrict__ W,
                                                            float* __restrict__ partials) {
    const int kgrp = blockIdx.x;
    const int t    = threadIdx.x;
    const int lane = t & 63;
    const int wave = t >> 6;       // 0..3

    __shared__ bf16x8 lds_b[KB_PER_GRP][64];                 // 4 KB
    __shared__ __align__(16) u16 xbuf[2][64][LROW];          // 34 KB

    XR A, B;
    load_stage(A, x, kgrp, 0, t);          // stage-0 loads hide under W bake

    // ---- phase 1: W -> B fragments in LDS ----
    {
        const int kbl  = t >> 6;
        const int head = lane & 15;
        const int kq   = lane >> 4;
        bf16x8 o = {0,0,0,0,0,0,0,0};
        if (head < HEADS) {
            float s0=0,s1=0,s2=0,s3=0,s4=0,s5=0,s6=0,s7=0;
            const float* wbase = W + (size_t)(head * DD) * IN_DIM
                               + kgrp * KFLOATS + kbl * 32 + kq * 8;
#pragma unroll
            for (int d = 0; d < DD; ++d) {
                const float4* p = (const float4*)(wbase + (size_t)d * IN_DIM);
                float4 lo = p[0], hi = p[1];
                s0 += lo.x; s1 += lo.y; s2 += lo.z; s3 += lo.w;
                s4 += hi.x; s5 += hi.y; s6 += hi.z; s7 += hi.w;
            }
            o[0]=f2bf(s0); o[1]=f2bf(s1); o[2]=f2bf(s2); o[3]=f2bf(s3);
            o[4]=f2bf(s4); o[5]=f2bf(s5); o[6]=f2bf(s6); o[7]=f2bf(s7);
        }
        lds_b[kbl][lane] = o;
    }
    __syncthreads();                      // lds_b ready

    const bf16x8 b0 = lds_b[0][lane];
    const bf16x8 b1 = lds_b[1][lane];
    const bf16x8 b2 = lds_b[2][lane];
    const bf16x8 b3 = lds_b[3][lane];

    write_stage(A, &xbuf[0][0][0], t);    // stage 0 -> buf0
    load_stage(B, x, kgrp, 1, t);         // stage 1 in flight
    __syncthreads();                      // buf0 ready

    const int head = lane & 15;
    const int r0   = (lane >> 4) * 4;
    const int kq   = lane >> 4;
    float* pbase = partials + (size_t)kgrp * PAIRS;
    const u16* rowp = &xbuf[0][0][0] + (size_t)(wave * 16 + (lane & 15)) * LROW + kq * 8;
    const size_t bufstride = (size_t)64 * LROW;

#define COMPUTE_STAGE(BUFIDX, MT)                                              \
    {                                                                          \
        const bf16x8* q = (const bf16x8*)(rowp + (BUFIDX) * bufstride);        \
        f32x4 acc = {0.f,0.f,0.f,0.f};                                         \
        acc = __builtin_amdgcn_mfma_f32_16x16x32_bf16(q[0],  b0, acc, 0,0,0);  \
        acc = __builtin_amdgcn_mfma_f32_16x16x32_bf16(q[4],  b1, acc, 0,0,0);  \
        acc = __builtin_amdgcn_mfma_f32_16x16x32_bf16(q[8],  b2, acc, 0,0,0);  \
        acc = __builtin_amdgcn_mfma_f32_16x16x32_bf16(q[12], b3, acc, 0,0,0);  \
        if (head < HEADS) {                                                    \
            _Pragma("unroll")                                                  \
            for (int j = 0; j < 4; ++j)                                        \
                pbase[(size_t)((MT)*16 + r0 + j) * HEADS + head] = acc[j];     \
        }                                                                      \
    }

    // ---- s=0: compute stage 0 (buf0), prefetch stage 2, write stage 1 ----
    load_stage(A, x, kgrp, 2, t);
    COMPUTE_STAGE(0, wave);
    __syncthreads();
    write_stage(B, &xbuf[1][0][0], t);
    __syncthreads();

    // ---- s=1: compute stage 1 (buf1), prefetch stage 3, write stage 2 ----
    load_stage(B, x, kgrp, 3, t);
    COMPUTE_STAGE(1, 4 + wave);
    __syncthreads();
    write_stage(A, &xbuf[0][0][0], t);
    __syncthreads();

    // ---- s=2: compute stage 2 (buf0), prefetch stage 4, write stage 3 ----
    load_stage(A, x, kgrp, 4, t);
    COMPUTE_STAGE(0, 8 + wave);
    __syncthreads();
    write_stage(B, &xbuf[1][0][0], t);
    __syncthreads();

    // ---- s=3: compute stage 3 (buf1), write stage 4 ----
    COMPUTE_STAGE(1, 12 + wave);
    __syncthreads();
    write_stage(A, &xbuf[0][0][0], t);
    __syncthreads();

    // ---- s=4: compute stage 4 (buf0) ----
    COMPUTE_STAGE(0, 16 + wave);
#undef COMPUTE_STAGE
}

// ---------------------------------------------------------------------------
// Finalize: tot[pair] = sum_g partials[g][pair];  pair = bn*8 + h
//           out[bn][h*10+m] = relu(tot * adj[bn][m])
// ---------------------------------------------------------------------------
__global__ __launch_bounds__(256) void finalize_kernel(const float* __restrict__ partials,
                                                       const float* __restrict__ adj,
                                                       float* __restrict__ out) {
    const int b  = blockIdx.x;       // 0..159
    const int t  = threadIdx.x;
    const int pr = t & 15;
    const int gs = t >> 4;           // 0..15 (each covers 32 kgrps)
    const int pair = b * 16 + pr;

    float s = 0.f;
    const float* p = partials + (size_t)gs * 32 * PAIRS + pair;
#pragma unroll 8
    for (int g = 0; g < 32; ++g)
        s += p[(size_t)g * PAIRS];

    __shared__ float red[16][16];
    red[gs][pr] = s;
    __syncthreads();

    if (t < 16) {
        float tot = 0.f;
#pragma unroll
        for (int i = 0; i < 16; ++i) tot += red[i][t];
        const int pair2 = b * 16 + t;
        const int bn = pair2 >> 3;
        const int h  = pair2 & 7;
        const float* a = adj + bn * NN;
        float* o = out + bn * (HEADS * NN) + h * NN;
#pragma unroll
        for (int m = 0; m < NN; ++m) {
            float v = tot * a[m];
            o[m] = v > 0.f ? v : 0.f;
        }
    }
}

extern "C" void kernel_launch(void* const* d_in, const int* in_sizes, int n_in,
                              void* d_out, int out_size, void* d_ws, size_t ws_size,
                              hipStream_t stream) {
    const float* x   = (const float*)d_in[0];   // (32,10,65536)
    const float* adj = (const float*)d_in[1];   // (32,10,10)
    const float* W   = (const float*)d_in[2];   // (64,65536)
    float* out = (float*)d_out;                 // (32,10,80)

    // workspace: partials (512 * 2560 f32 = 5.24 MB)
    float* partials = (float*)d_ws;

    gemv_fused_kernel<<<KGRPS, 256, 0, stream>>>(x, W, partials);
    finalize_kernel<<<160, 256, 0, stream>>>(partials, adj, out);
}